// Round 2
// baseline (1639.951 us; speedup 1.0000x reference)
//
#include <hip/hip_runtime.h>
#include <hip/hip_bf16.h>
#include <stdint.h>

#define DM 2048
#define DF 8192
#define NT 8192

typedef unsigned short u16;
typedef __attribute__((ext_vector_type(8))) __bf16 bf16x8;
typedef __attribute__((ext_vector_type(4))) float f32x4;

typedef __attribute__((address_space(1))) uint8_t ga_u8_t;
typedef __attribute__((address_space(3))) uint8_t lds_u8_t;

__device__ __forceinline__ void async_cp16(const void* g, void* l) {
  __builtin_amdgcn_global_load_lds((ga_u8_t*)g, (lds_u8_t*)l, 16, 0, 0);
}

__device__ __forceinline__ u16 f2b(float f) {
  unsigned int u = __builtin_bit_cast(unsigned int, f);
  u = (u + 0x7fffu + ((u >> 16) & 1u)) >> 16;
  return (u16)u;
}
__device__ __forceinline__ float gelu_f(float x) {
  return 0.5f * x * (1.0f + erff(x * 0.70710678118654752f));
}

// -------- per-token combined gate weights: wtok[t] = (w0_eff, w1_eff) --------
__global__ void prep_wtok(const int* __restrict__ eid, const float* __restrict__ w,
                          float2* __restrict__ wtok, int n) {
  int i = blockIdx.x * blockDim.x + threadIdx.x;
  if (i >= n) return;
  float a = 0.f, b = 0.f;
  int e0 = eid[2 * i] & 1, e1 = eid[2 * i + 1] & 1;
  float w0 = w[2 * i], w1 = w[2 * i + 1];
  if (e0) b += w0; else a += w0;
  if (e1) b += w1; else a += w1;
  wtok[i] = make_float2(a, b);
}

// -------- fp32 -> bf16 elementwise (x -> Xb) --------
__global__ void conv_f32_bf16(const float* __restrict__ in, u16* __restrict__ out,
                              int n4) {
  int i = blockIdx.x * blockDim.x + threadIdx.x;
  if (i >= n4) return;
  float4 v = reinterpret_cast<const float4*>(in)[i];
  ushort4 o;
  o.x = f2b(v.x); o.y = f2b(v.y); o.z = f2b(v.z); o.w = f2b(v.w);
  reinterpret_cast<ushort4*>(out)[i] = o;
}

// -------- fp32 transpose+convert: in (R x Cc) fp32 -> out (Cc x R) bf16 --------
__global__ void transpose_conv(const float* __restrict__ in, u16* __restrict__ out,
                               int R, int Cc) {
  __shared__ float tile[32][33];
  int tx = threadIdx.x & 31, ty = threadIdx.x >> 5;  // 256 threads: 32x8
  int r0 = blockIdx.y * 32, c0 = blockIdx.x * 32;
#pragma unroll
  for (int i = 0; i < 32; i += 8)
    tile[ty + i][tx] = in[(size_t)(r0 + ty + i) * Cc + c0 + tx];
  __syncthreads();
#pragma unroll
  for (int i = 0; i < 32; i += 8)
    out[(size_t)(c0 + ty + i) * R + r0 + tx] = f2b(tile[tx][ty + i]);
}

__global__ void fill_sentinel(float* p, int n) {
  int i = blockIdx.x * blockDim.x + threadIdx.x;
  if (i < n) p[i] = 0.125f;
}

// -------- C = A(MxK) @ Bt(NxK)^T, bf16 in, fp32 accum --------
// MODE 0: C(bf16) = bf16( gelu(acc + bias[col]) * w_eff[t] )   (GEMM1 -> H)
// MODE 1: C(f32)  = acc + w_eff[t]*bias[col]                   (GEMM2, expert 0)
// MODE 2: C(f32) += acc + w_eff[t]*bias[col]                   (GEMM2, expert 1)
template <int MODE>
__global__ void gemm_bt(const u16* __restrict__ A, const u16* __restrict__ Bt,
                        void* __restrict__ Cv, const float2* __restrict__ wtok,
                        const float* __restrict__ bias,
                        int M, int N, int K, int sel) {
  __shared__ __align__(16) u16 As[128 * 32];
  __shared__ __align__(16) u16 Bs[128 * 32];
  const int tid = threadIdx.x;
  const int wave = tid >> 6;
  const int lane = tid & 63;
  const int m0 = blockIdx.y * 128;
  const int n0 = blockIdx.x * 128;

  // ---- staging: global_load_lds, 16B/lane, wave-uniform LDS base ----
  // LDS layout: [128 rows][32 k] (64 B/row); 16B k-groups XOR-swizzled by
  // (row>>1)&3 so fragment ds_read_b128 is only 2-way bank-aliased (free, m136).
  const int l2 = lane >> 2;
  const int p = lane & 3;
  const u16* gA[2]; const u16* gB[2]; char* lA[2]; char* lB[2];
#pragma unroll
  for (int j = 0; j < 2; ++j) {
    int chunk = j * 4 + wave;          // 0..7, each = 16 rows = 1024 B
    int row = chunk * 16 + l2;
    int q = p ^ ((row >> 1) & 3);      // logical k-group stored at slot p
    gA[j] = A + (size_t)(m0 + row) * K + q * 8;
    gB[j] = Bt + (size_t)(n0 + row) * K + q * 8;
    lA[j] = (char*)As + chunk * 1024;
    lB[j] = (char*)Bs + chunk * 1024;
  }

  // ---- fragment read addresses ----
  const int fr = lane & 15;
  const int qw = lane >> 4;
  const int wRow = (wave >> 1) * 64;
  const int wCol = (wave & 1) * 64;
  uint32_t aAddr[4], bAddr[4];
#pragma unroll
  for (int i = 0; i < 4; ++i) {
    int ra = wRow + i * 16 + fr;
    aAddr[i] = ra * 64 + (qw ^ ((ra >> 1) & 3)) * 16;
    int rb = wCol + i * 16 + fr;
    bAddr[i] = rb * 64 + (qw ^ ((rb >> 1) & 3)) * 16;
  }

  f32x4 acc[4][4] = {};

  for (int k0 = 0; k0 < K; k0 += 32) {
    async_cp16(gA[0] + k0, lA[0]);
    async_cp16(gA[1] + k0, lA[1]);
    async_cp16(gB[0] + k0, lB[0]);
    async_cp16(gB[1] + k0, lB[1]);
    __syncthreads();
    bf16x8 af[4], bfr[4];
#pragma unroll
    for (int i = 0; i < 4; ++i)
      af[i] = *reinterpret_cast<const bf16x8*>((const char*)As + aAddr[i]);
#pragma unroll
    for (int j = 0; j < 4; ++j)
      bfr[j] = *reinterpret_cast<const bf16x8*>((const char*)Bs + bAddr[j]);
#pragma unroll
    for (int i = 0; i < 4; ++i)
#pragma unroll
      for (int j = 0; j < 4; ++j)
        // swapped operands -> lane&15 = token (m), (lane>>4)*4+reg = col (n):
        // each lane's 4 regs are 4 CONTIGUOUS output cols -> vector stores
        acc[i][j] = __builtin_amdgcn_mfma_f32_16x16x32_bf16(bfr[j], af[i],
                                                            acc[i][j], 0, 0, 0);
    __syncthreads();
  }

  // ---- epilogue ----
#pragma unroll
  for (int i = 0; i < 4; ++i) {
    int t = m0 + wRow + i * 16 + fr;
    float2 wt = wtok[t];
    float ws = sel ? wt.y : wt.x;
#pragma unroll
    for (int j = 0; j < 4; ++j) {
      int col0 = n0 + wCol + j * 16 + qw * 4;
      float4 bb = *reinterpret_cast<const float4*>(bias + col0);
      f32x4 a = acc[i][j];
      if (MODE == 0) {
        u16* C = (u16*)Cv;
        ushort4 o;
        o.x = f2b(gelu_f(a.x + bb.x) * ws);
        o.y = f2b(gelu_f(a.y + bb.y) * ws);
        o.z = f2b(gelu_f(a.z + bb.z) * ws);
        o.w = f2b(gelu_f(a.w + bb.w) * ws);
        *reinterpret_cast<ushort4*>(C + (size_t)t * N + col0) = o;
      } else {
        float* C = (float*)Cv;
        float4 o;
        o.x = a.x + ws * bb.x;
        o.y = a.y + ws * bb.y;
        o.z = a.z + ws * bb.z;
        o.w = a.w + ws * bb.w;
        if (MODE == 2) {
          float4 pv = *reinterpret_cast<const float4*>(C + (size_t)t * N + col0);
          o.x += pv.x; o.y += pv.y; o.z += pv.z; o.w += pv.w;
        }
        *reinterpret_cast<float4*>(C + (size_t)t * N + col0) = o;
      }
    }
  }
}

extern "C" void kernel_launch(void* const* d_in, const int* in_sizes, int n_in,
                              void* d_out, int out_size, void* d_ws, size_t ws_size,
                              hipStream_t stream) {
  const float* x    = (const float*)d_in[0];
  const int*   eid  = (const int*)d_in[1];
  const float* topw = (const float*)d_in[2];
  const float* W1_0 = (const float*)d_in[3];
  const float* b1_0 = (const float*)d_in[4];
  const float* W2_0 = (const float*)d_in[5];
  const float* b2_0 = (const float*)d_in[6];
  const float* W1_1 = (const float*)d_in[7];
  const float* b1_1 = (const float*)d_in[8];
  const float* W2_1 = (const float*)d_in[9];
  const float* b2_1 = (const float*)d_in[10];
  float* out = (float*)d_out;

  char* ws = (char*)d_ws;
  const size_t SZ_WT = (size_t)DM * DF * sizeof(u16);  // 32 MiB
  size_t off = (size_t)NT * sizeof(float2);            // 64 KiB
  float2* wtok = (float2*)ws;
  u16* Xb  = (u16*)(ws + off); off += (size_t)NT * DM * sizeof(u16);  // 32 MiB
  u16* WTa = (u16*)(ws + off); off += SZ_WT;                           // 32 MiB
  u16* WTb = (u16*)(ws + off); off += SZ_WT;                           // 32 MiB
  u16* H   = (u16*)(ws + off); off += (size_t)NT * DF * sizeof(u16);  // 128 MiB

  if (ws_size < off) {
    fill_sentinel<<<(out_size + 255) / 256, 256, 0, stream>>>(out, out_size);
    return;
  }

  prep_wtok<<<(NT + 255) / 256, 256, 0, stream>>>(eid, topw, wtok, NT);
  conv_f32_bf16<<<(NT * DM / 4 + 255) / 256, 256, 0, stream>>>(x, Xb, NT * DM / 4);

  dim3 g1(DF / 128, NT / 128);  // (64, 64)
  dim3 g2(DM / 128, NT / 128);  // (16, 64)

  // expert 0
  transpose_conv<<<dim3(DF / 32, DM / 32), 256, 0, stream>>>(W1_0, WTa, DM, DF);
  gemm_bt<0><<<g1, 256, 0, stream>>>(Xb, WTa, H, wtok, b1_0, NT, DF, DM, 0);
  transpose_conv<<<dim3(DM / 32, DF / 32), 256, 0, stream>>>(W2_0, WTb, DF, DM);
  gemm_bt<1><<<g2, 256, 0, stream>>>(H, WTb, out, wtok, b2_0, NT, DM, DF, 0);
  // expert 1
  transpose_conv<<<dim3(DF / 32, DM / 32), 256, 0, stream>>>(W1_1, WTa, DM, DF);
  gemm_bt<0><<<g1, 256, 0, stream>>>(Xb, WTa, H, wtok, b1_1, NT, DF, DM, 1);
  transpose_conv<<<dim3(DM / 32, DF / 32), 256, 0, stream>>>(W2_1, WTb, DF, DM);
  gemm_bt<2><<<g2, 256, 0, stream>>>(H, WTb, out, wtok, b2_1, NT, DM, DF, 1);
}

// Round 3
// 1459.499 us; speedup vs baseline: 1.1236x; 1.1236x over previous
//
#include <hip/hip_runtime.h>
#include <hip/hip_bf16.h>
#include <stdint.h>

#define DM 2048
#define DF 8192
#define NT 8192

typedef unsigned short u16;
typedef __attribute__((ext_vector_type(8))) __bf16 bf16x8;
typedef __attribute__((ext_vector_type(4))) float f32x4;

typedef __attribute__((address_space(1))) uint8_t ga_u8_t;
typedef __attribute__((address_space(3))) uint8_t lds_u8_t;

__device__ __forceinline__ void async_cp16(const void* g, void* l) {
  __builtin_amdgcn_global_load_lds((ga_u8_t*)g, (lds_u8_t*)l, 16, 0, 0);
}

__device__ __forceinline__ u16 f2b(float f) {
  unsigned int u = __builtin_bit_cast(unsigned int, f);
  u = (u + 0x7fffu + ((u >> 16) & 1u)) >> 16;
  return (u16)u;
}
__device__ __forceinline__ float gelu_f(float x) {
  return 0.5f * x * (1.0f + erff(x * 0.70710678118654752f));
}

// -------- per-token combined gate weights: wtok[t] = (w0_eff, w1_eff) --------
__global__ void prep_wtok(const int* __restrict__ eid, const float* __restrict__ w,
                          float2* __restrict__ wtok, int n) {
  int i = blockIdx.x * blockDim.x + threadIdx.x;
  if (i >= n) return;
  float a = 0.f, b = 0.f;
  int e0 = eid[2 * i] & 1, e1 = eid[2 * i + 1] & 1;
  float w0 = w[2 * i], w1 = w[2 * i + 1];
  if (e0) b += w0; else a += w0;
  if (e1) b += w1; else a += w1;
  wtok[i] = make_float2(a, b);
}

// -------- fp32 -> bf16 elementwise (x -> Xb) --------
__global__ void conv_f32_bf16(const float* __restrict__ in, u16* __restrict__ out,
                              int n4) {
  int i = blockIdx.x * blockDim.x + threadIdx.x;
  if (i >= n4) return;
  float4 v = reinterpret_cast<const float4*>(in)[i];
  ushort4 o;
  o.x = f2b(v.x); o.y = f2b(v.y); o.z = f2b(v.z); o.w = f2b(v.w);
  reinterpret_cast<ushort4*>(out)[i] = o;
}

// -------- fp32 transpose+convert: in (R x Cc) fp32 -> out (Cc x R) bf16 --------
__global__ void transpose_conv(const float* __restrict__ in, u16* __restrict__ out,
                               int R, int Cc) {
  __shared__ float tile[32][33];
  int tx = threadIdx.x & 31, ty = threadIdx.x >> 5;  // 256 threads: 32x8
  int r0 = blockIdx.y * 32, c0 = blockIdx.x * 32;
#pragma unroll
  for (int i = 0; i < 32; i += 8)
    tile[ty + i][tx] = in[(size_t)(r0 + ty + i) * Cc + c0 + tx];
  __syncthreads();
#pragma unroll
  for (int i = 0; i < 32; i += 8)
    out[(size_t)(c0 + ty + i) * R + r0 + tx] = f2b(tile[tx][ty + i]);
}

__global__ void fill_sentinel(float* p, int n) {
  int i = blockIdx.x * blockDim.x + threadIdx.x;
  if (i < n) p[i] = 0.125f;
}

// -------- C = A(MxK) @ Bt(NxK)^T, bf16 in, fp32 accum, BK=64 --------
// MODE 0: C(bf16) = bf16( gelu(acc + bias[col]) * w_eff[t] )   (GEMM1 -> H)
// MODE 1: C(f32)  = acc + w_eff[t]*bias[col]                   (GEMM2, expert 0)
// MODE 2: C(f32) += acc + w_eff[t]*bias[col]                   (GEMM2, expert 1)
template <int MODE>
__global__ void gemm_bt(const u16* __restrict__ A, const u16* __restrict__ Bt,
                        void* __restrict__ Cv, const float2* __restrict__ wtok,
                        const float* __restrict__ bias,
                        int M, int N, int K, int sel) {
  // BK=64: 128 rows x 64 k x 2B = 16 KB each; 32 KB total -> >=4 blocks/CU.
  // Doubles MFMA per vmcnt(0)+barrier drain vs BK=32 (the R2 54% stall).
  __shared__ __align__(16) u16 As[128 * 64];
  __shared__ __align__(16) u16 Bs[128 * 64];
  const int tid = threadIdx.x;
  const int wave = tid >> 6;
  const int lane = tid & 63;
  const int m0 = blockIdx.y * 128;
  const int n0 = blockIdx.x * 128;

  // ---- staging: global_load_lds 16B/lane, wave-uniform LDS base ----
  // Row = 128 B (8 x 16B slots). Physical slot of logical k-group g in row r
  // is g ^ (r&7): fragment ds_read_b128 becomes 2-way bank-aliased (free,
  // m136) while LDS dest stays lane-contiguous (lane*16 = (lane>>3)*128 +
  // (lane&7)*16), as global_load_lds requires (m104/m108).
  const int r8 = lane >> 3;           // row within 8-row chunk
  const int p = lane & 7;             // physical slot
  const int q = p ^ r8;               // logical k-group fetched by this lane
  const u16* gA[4]; const u16* gB[4]; char* lA[4]; char* lB[4];
#pragma unroll
  for (int j = 0; j < 4; ++j) {
    int chunk = j * 4 + wave;         // 0..15, each = 8 rows = 1 KB
    int row = chunk * 8 + r8;
    gA[j] = A + (size_t)(m0 + row) * K + q * 8;
    gB[j] = Bt + (size_t)(n0 + row) * K + q * 8;
    lA[j] = (char*)As + chunk * 1024;
    lB[j] = (char*)Bs + chunk * 1024;
  }

  // ---- fragment read addresses (kk=0 half; kk=1 is addr ^ 64) ----
  const int fr = lane & 15;
  const int qw = lane >> 4;
  const int wRow = (wave >> 1) * 64;
  const int wCol = (wave & 1) * 64;
  uint32_t aAddr[4], bAddr[4];
#pragma unroll
  for (int i = 0; i < 4; ++i) {
    int ra = wRow + i * 16 + fr;
    aAddr[i] = ra * 128 + ((qw ^ (ra & 7)) * 16);
    int rb = wCol + i * 16 + fr;
    bAddr[i] = rb * 128 + ((qw ^ (rb & 7)) * 16);
  }

  f32x4 acc[4][4] = {};

  for (int k0 = 0; k0 < K; k0 += 64) {
#pragma unroll
    for (int j = 0; j < 4; ++j) async_cp16(gA[j] + k0, lA[j]);
#pragma unroll
    for (int j = 0; j < 4; ++j) async_cp16(gB[j] + k0, lB[j]);
    __syncthreads();
#pragma unroll
    for (int kk = 0; kk < 2; ++kk) {
      const uint32_t kx = kk << 6;    // slot bit2 flip == addr ^ 64
      bf16x8 af[4], bfr[4];
#pragma unroll
      for (int i = 0; i < 4; ++i)
        af[i] = *reinterpret_cast<const bf16x8*>((const char*)As + (aAddr[i] ^ kx));
#pragma unroll
      for (int j = 0; j < 4; ++j)
        bfr[j] = *reinterpret_cast<const bf16x8*>((const char*)Bs + (bAddr[j] ^ kx));
#pragma unroll
      for (int i = 0; i < 4; ++i)
#pragma unroll
        for (int j = 0; j < 4; ++j)
          // swapped operands -> lane&15 = token (m), (lane>>4)*4+reg = col:
          // each lane's 4 regs are 4 CONTIGUOUS output cols -> vector stores
          acc[i][j] = __builtin_amdgcn_mfma_f32_16x16x32_bf16(bfr[j], af[i],
                                                              acc[i][j], 0, 0, 0);
    }
    __syncthreads();
  }

  // ---- epilogue ----
#pragma unroll
  for (int i = 0; i < 4; ++i) {
    int t = m0 + wRow + i * 16 + fr;
    float2 wt = wtok[t];
    float ws = sel ? wt.y : wt.x;
#pragma unroll
    for (int j = 0; j < 4; ++j) {
      int col0 = n0 + wCol + j * 16 + qw * 4;
      float4 bb = *reinterpret_cast<const float4*>(bias + col0);
      f32x4 a = acc[i][j];
      if (MODE == 0) {
        u16* C = (u16*)Cv;
        ushort4 o;
        o.x = f2b(gelu_f(a.x + bb.x) * ws);
        o.y = f2b(gelu_f(a.y + bb.y) * ws);
        o.z = f2b(gelu_f(a.z + bb.z) * ws);
        o.w = f2b(gelu_f(a.w + bb.w) * ws);
        *reinterpret_cast<ushort4*>(C + (size_t)t * N + col0) = o;
      } else {
        float* C = (float*)Cv;
        float4 o;
        o.x = a.x + ws * bb.x;
        o.y = a.y + ws * bb.y;
        o.z = a.z + ws * bb.z;
        o.w = a.w + ws * bb.w;
        if (MODE == 2) {
          float4 pv = *reinterpret_cast<const float4*>(C + (size_t)t * N + col0);
          o.x += pv.x; o.y += pv.y; o.z += pv.z; o.w += pv.w;
        }
        *reinterpret_cast<float4*>(C + (size_t)t * N + col0) = o;
      }
    }
  }
}

extern "C" void kernel_launch(void* const* d_in, const int* in_sizes, int n_in,
                              void* d_out, int out_size, void* d_ws, size_t ws_size,
                              hipStream_t stream) {
  const float* x    = (const float*)d_in[0];
  const int*   eid  = (const int*)d_in[1];
  const float* topw = (const float*)d_in[2];
  const float* W1_0 = (const float*)d_in[3];
  const float* b1_0 = (const float*)d_in[4];
  const float* W2_0 = (const float*)d_in[5];
  const float* b2_0 = (const float*)d_in[6];
  const float* W1_1 = (const float*)d_in[7];
  const float* b1_1 = (const float*)d_in[8];
  const float* W2_1 = (const float*)d_in[9];
  const float* b2_1 = (const float*)d_in[10];
  float* out = (float*)d_out;

  char* ws = (char*)d_ws;
  const size_t SZ_WT = (size_t)DM * DF * sizeof(u16);  // 32 MiB
  size_t off = (size_t)NT * sizeof(float2);            // 64 KiB
  float2* wtok = (float2*)ws;
  u16* Xb  = (u16*)(ws + off); off += (size_t)NT * DM * sizeof(u16);  // 32 MiB
  u16* WTa = (u16*)(ws + off); off += SZ_WT;                           // 32 MiB
  u16* WTb = (u16*)(ws + off); off += SZ_WT;                           // 32 MiB
  u16* H   = (u16*)(ws + off); off += (size_t)NT * DF * sizeof(u16);  // 128 MiB

  if (ws_size < off) {
    fill_sentinel<<<(out_size + 255) / 256, 256, 0, stream>>>(out, out_size);
    return;
  }

  prep_wtok<<<(NT + 255) / 256, 256, 0, stream>>>(eid, topw, wtok, NT);
  conv_f32_bf16<<<(NT * DM / 4 + 255) / 256, 256, 0, stream>>>(x, Xb, NT * DM / 4);

  dim3 g1(DF / 128, NT / 128);  // (64, 64)
  dim3 g2(DM / 128, NT / 128);  // (16, 64)

  // expert 0
  transpose_conv<<<dim3(DF / 32, DM / 32), 256, 0, stream>>>(W1_0, WTa, DM, DF);
  gemm_bt<0><<<g1, 256, 0, stream>>>(Xb, WTa, H, wtok, b1_0, NT, DF, DM, 0);
  transpose_conv<<<dim3(DM / 32, DF / 32), 256, 0, stream>>>(W2_0, WTb, DF, DM);
  gemm_bt<1><<<g2, 256, 0, stream>>>(H, WTb, out, wtok, b2_0, NT, DM, DF, 0);
  // expert 1
  transpose_conv<<<dim3(DF / 32, DM / 32), 256, 0, stream>>>(W1_1, WTa, DM, DF);
  gemm_bt<0><<<g1, 256, 0, stream>>>(Xb, WTa, H, wtok, b1_1, NT, DF, DM, 1);
  transpose_conv<<<dim3(DM / 32, DF / 32), 256, 0, stream>>>(W2_1, WTb, DF, DM);
  gemm_bt<2><<<g2, 256, 0, stream>>>(H, WTb, out, wtok, b2_1, NT, DM, DF, 1);
}